// Round 1
// baseline (60.561 us; speedup 1.0000x reference)
//
#include <hip/hip_runtime.h>
#include <stdint.h>

typedef __attribute__((ext_vector_type(8))) short bf16x8;
typedef __attribute__((ext_vector_type(4))) float f32x4;

#define NROWS 4096
#define DDIM  1024
#define NB    32        // 4096 / 128 tiles
#define NBLK  528       // NB*(NB+1)/2 triangular tiles
#define COS_EPS 1e-8f

__device__ __forceinline__ ushort f2bf(float x) {
  union { float f; uint32_t u; } v; v.f = x;
  uint32_t r = (v.u + 0x7FFF + ((v.u >> 16) & 1)) >> 16;  // round-to-nearest-even
  return (ushort)r;
}

// ---------------- prep: sq, 1/norm, bf16 copy ----------------
extern "C" __global__ void __launch_bounds__(256) prep_kernel(
    const float* __restrict__ F, ushort* __restrict__ Fb,
    float* __restrict__ sq, float* __restrict__ rn) {
  const int row  = blockIdx.x * 4 + (threadIdx.x >> 6);
  const int lane = threadIdx.x & 63;
  const float4* src = (const float4*)(F + (size_t)row * DDIM);
  ushort4* dst = (ushort4*)(Fb + (size_t)row * DDIM);
  float s = 0.f;
#pragma unroll
  for (int it = 0; it < 4; ++it) {
    float4 v = src[it * 64 + lane];
    s += v.x * v.x + v.y * v.y + v.z * v.z + v.w * v.w;
    ushort4 b;
    b.x = f2bf(v.x); b.y = f2bf(v.y); b.z = f2bf(v.z); b.w = f2bf(v.w);
    dst[it * 64 + lane] = b;
  }
#pragma unroll
  for (int off = 32; off; off >>= 1) s += __shfl_down(s, off);
  if (lane == 0) {
    sq[row] = s;
    rn[row] = 1.0f / fmaxf(sqrtf(s), COS_EPS);
  }
}

// ---------------- fused gram (bf16 MFMA) + loss epilogue ----------------
extern "C" __global__ void __launch_bounds__(256) gram_kernel(
    const ushort* __restrict__ Fb, const float* __restrict__ sq,
    const float* __restrict__ rn, const int* __restrict__ y,
    float* __restrict__ partials) {
  __shared__ __align__(16) ushort As[128 * 32];
  __shared__ __align__(16) ushort Bs[128 * 32];

  // decode triangular tile index: bi <= bj
  int t = blockIdx.x, bi = 0;
  while (t >= NB - bi) { t -= NB - bi; ++bi; }
  const int bj = bi + t;

  const int tid  = threadIdx.x;
  const int lane = tid & 63;
  const int wid  = tid >> 6;
  const int wrow = wid >> 1;   // 2x2 wave grid, each wave 64x64 out
  const int wcol = wid & 1;

  f32x4 acc[4][4] = {};

  // per-thread staging offsets (row within 64-row chunk, 8-bf16 col group)
  const int srow = wid * 16 + (lane >> 2);
  const int scol = (lane & 3) * 8;

  for (int k0 = 0; k0 < DDIM; k0 += 32) {
#pragma unroll
    for (int q = 0; q < 2; ++q) {
      const ushort* ga = Fb + (size_t)(bi * 128 + q * 64 + srow) * DDIM + k0 + scol;
      const ushort* gb = Fb + (size_t)(bj * 128 + q * 64 + srow) * DDIM + k0 + scol;
      ushort* la = As + (q * 64 + wid * 16) * 32;   // wave-uniform LDS base
      ushort* lb = Bs + (q * 64 + wid * 16) * 32;
      __builtin_amdgcn_global_load_lds(
          (const __attribute__((address_space(1))) uint32_t*)ga,
          (__attribute__((address_space(3))) uint32_t*)la, 16, 0, 0);
      __builtin_amdgcn_global_load_lds(
          (const __attribute__((address_space(1))) uint32_t*)gb,
          (__attribute__((address_space(3))) uint32_t*)lb, 16, 0, 0);
    }
    __syncthreads();

    bf16x8 a[4], b[4];
#pragma unroll
    for (int m = 0; m < 4; ++m) {
      a[m] = *(const bf16x8*)(As + (wrow * 64 + m * 16 + (lane & 15)) * 32 + (lane >> 4) * 8);
      b[m] = *(const bf16x8*)(Bs + (wcol * 64 + m * 16 + (lane & 15)) * 32 + (lane >> 4) * 8);
    }
#pragma unroll
    for (int m = 0; m < 4; ++m)
#pragma unroll
      for (int n = 0; n < 4; ++n)
        acc[m][n] = __builtin_amdgcn_mfma_f32_16x16x32_bf16(a[m], b[n], acc[m][n], 0, 0, 0);
    __syncthreads();
  }

  // ---------- epilogue ----------
  const int rbase = bi * 128 + wrow * 64;
  const int cbase = bj * 128 + wcol * 64;
  const float w = (bi == bj) ? 1.0f : 2.0f;

  // hoist per-lane row/col metadata
  float sqr[16], rnr[16];
  int   yr[16];
#pragma unroll
  for (int m = 0; m < 4; ++m)
#pragma unroll
    for (int v = 0; v < 4; ++v) {
      int gi = rbase + m * 16 + (lane >> 4) * 4 + v;
      sqr[m * 4 + v] = sq[gi];
      rnr[m * 4 + v] = rn[gi];
      yr[m * 4 + v]  = y[gi];
    }
  float sqc[4], rnc[4];
  int   yc[4];
#pragma unroll
  for (int n = 0; n < 4; ++n) {
    int gj = cbase + n * 16 + (lane & 15);
    sqc[n] = sq[gj];
    rnc[n] = rn[gj];
    yc[n]  = y[gj];
  }

  float lsum = 0.f;
#pragma unroll
  for (int m = 0; m < 4; ++m)
#pragma unroll
    for (int n = 0; n < 4; ++n)
#pragma unroll
      for (int v = 0; v < 4; ++v) {
        float g  = acc[m][n][v];
        float d2 = sqr[m * 4 + v] + sqc[n] - 2.0f * g;
        float dist = d2 > 0.f ? sqrtf(d2) : 0.f;
        float sim  = g * rnr[m * 4 + v] * rnc[n];
        float sgn  = (yr[m * 4 + v] == yc[n]) ? 1.0f : -1.0f;
        lsum += sgn * (dist - sim);
      }
  lsum *= w;

#pragma unroll
  for (int off = 32; off; off >>= 1) lsum += __shfl_down(lsum, off);
  __shared__ float wsum[4];
  if (lane == 0) wsum[wid] = lsum;
  __syncthreads();
  if (tid == 0) partials[blockIdx.x] = wsum[0] + wsum[1] + wsum[2] + wsum[3];
}

// ---------------- deterministic final reduce ----------------
extern "C" __global__ void __launch_bounds__(256) reduce_kernel(
    const float* __restrict__ partials, float* __restrict__ out) {
  float s = 0.f;
  for (int i = threadIdx.x; i < NBLK; i += 256) s += partials[i];
#pragma unroll
  for (int off = 32; off; off >>= 1) s += __shfl_down(s, off);
  __shared__ float ws[4];
  if ((threadIdx.x & 63) == 0) ws[threadIdx.x >> 6] = s;
  __syncthreads();
  if (threadIdx.x == 0) out[0] = ws[0] + ws[1] + ws[2] + ws[3];
}

extern "C" void kernel_launch(void* const* d_in, const int* in_sizes, int n_in,
                              void* d_out, int out_size, void* d_ws, size_t ws_size,
                              hipStream_t stream) {
  const float* F = (const float*)d_in[0];
  const int*   y = (const int*)d_in[1];
  float* out = (float*)d_out;

  // ws layout: bf16 features | sq | rn | partials
  ushort* Fb = (ushort*)d_ws;                                 // 8 MB
  float*  sq = (float*)((char*)d_ws + (size_t)NROWS * DDIM * 2);
  float*  rn = sq + NROWS;
  float*  partials = rn + NROWS;

  prep_kernel<<<NROWS / 4, 256, 0, stream>>>(F, Fb, sq, rn);
  gram_kernel<<<NBLK, 256, 0, stream>>>(Fb, sq, rn, y, partials);
  reduce_kernel<<<1, 256, 0, stream>>>(partials, out);
}

// Round 2
// 54.972 us; speedup vs baseline: 1.1017x; 1.1017x over previous
//
#include <hip/hip_runtime.h>
#include <stdint.h>

typedef __attribute__((ext_vector_type(8))) short bf16x8;
typedef __attribute__((ext_vector_type(4))) float f32x4;

#define NROWS 4096
#define DDIM  1024
#define NB    32        // 4096 / 128 tiles
#define NBLK  528       // NB*(NB+1)/2 triangular tiles
#define COS_EPS 1e-8f

__device__ __forceinline__ ushort f2bf(float x) {
  union { float f; uint32_t u; } v; v.f = x;
  uint32_t r = (v.u + 0x7FFF + ((v.u >> 16) & 1)) >> 16;  // RNE
  return (ushort)r;
}

__device__ __forceinline__ void gload16(const ushort* g, ushort* l) {
  __builtin_amdgcn_global_load_lds(
      (const __attribute__((address_space(1))) uint32_t*)g,
      (__attribute__((address_space(3))) uint32_t*)l, 16, 0, 0);
}

// ---------------- prep: sq, 1/norm, bf16 copy ----------------
extern "C" __global__ void __launch_bounds__(256) prep_kernel(
    const float* __restrict__ F, ushort* __restrict__ Fb,
    float* __restrict__ sq, float* __restrict__ rn) {
  const int row  = blockIdx.x * 4 + (threadIdx.x >> 6);
  const int lane = threadIdx.x & 63;
  const float4* src = (const float4*)(F + (size_t)row * DDIM);
  ushort4* dst = (ushort4*)(Fb + (size_t)row * DDIM);
  float s = 0.f;
#pragma unroll
  for (int it = 0; it < 4; ++it) {
    float4 v = src[it * 64 + lane];
    s += v.x * v.x + v.y * v.y + v.z * v.z + v.w * v.w;
    ushort4 b;
    b.x = f2bf(v.x); b.y = f2bf(v.y); b.z = f2bf(v.z); b.w = f2bf(v.w);
    dst[it * 64 + lane] = b;
  }
#pragma unroll
  for (int off = 32; off; off >>= 1) s += __shfl_down(s, off);
  if (lane == 0) {
    sq[row] = s;
    rn[row] = 1.0f / fmaxf(sqrtf(s), COS_EPS);
  }
}

// ---------------- fused gram (bf16 MFMA) + loss epilogue ----------------
// 128x128 tile, BK=64, double-buffered 2-phase pipeline, XOR-swizzled LDS.
extern "C" __global__ void __launch_bounds__(256) gram_kernel(
    const ushort* __restrict__ Fb, const float* __restrict__ sq,
    const float* __restrict__ rn, const int* __restrict__ y,
    float* __restrict__ partials) {
  // [2 bufs][128 rows][64 bf16]  (rows are 128B; chunk = 16B unit)
  __shared__ __align__(16) ushort As[2][128 * 64];
  __shared__ __align__(16) ushort Bs[2][128 * 64];

  // decode triangular tile index: bi <= bj
  int t = blockIdx.x, bi = 0;
  while (t >= NB - bi) { t -= NB - bi; ++bi; }
  const int bj = bi + t;

  const int tid  = threadIdx.x;
  const int lane = tid & 63;
  const int wid  = tid >> 6;
  const int wrow = wid >> 1;   // 2x2 wave grid, each wave 64x64 out
  const int wcol = wid & 1;

  f32x4 acc[4][4] = {};

  // ---- staging addresses (pre-swizzled global source, rule #21) ----
  // thread stages LDS linear slot (row = tid>>3, chunk' = tid&7);
  // that slot must hold global chunk  chunk'^ (row&7).
  const int srow = tid >> 3;                       // row within 32-row issue
  const int gcol = (((tid & 7) ^ (srow & 7)) * 8); // swizzled source col (elems)
  const int rowA = bi * 128 + srow;
  const int rowB = bj * 128 + srow;
  const int lbase = wid * 512;                     // ushort units: wid*8 rows

  // ---- fragment read offsets (ushort units), swizzled chunk ----
  int aoff[4], boff[4], coff[2];
#pragma unroll
  for (int m = 0; m < 4; ++m) {
    aoff[m] = (wrow * 64 + m * 16 + (lane & 15)) * 64;
    boff[m] = (wcol * 64 + m * 16 + (lane & 15)) * 64;
  }
#pragma unroll
  for (int kk = 0; kk < 2; ++kk)
    coff[kk] = ((kk * 4 + (lane >> 4)) ^ (lane & 7)) * 8;

#define STAGE(bufsel, kt) do {                                              \
    const int _k0 = (kt) * 64;                                              \
    _Pragma("unroll")                                                       \
    for (int _it = 0; _it < 4; ++_it) {                                     \
      gload16(Fb + (size_t)(rowA + _it * 32) * DDIM + _k0 + gcol,           \
              &As[bufsel][_it * 2048 + lbase]);                             \
      gload16(Fb + (size_t)(rowB + _it * 32) * DDIM + _k0 + gcol,           \
              &Bs[bufsel][_it * 2048 + lbase]);                             \
    }                                                                       \
  } while (0)

#define COMPUTE(bufsel) do {                                                \
    _Pragma("unroll")                                                       \
    for (int _kk = 0; _kk < 2; ++_kk) {                                     \
      bf16x8 _av[4], _bv[4];                                                \
      _Pragma("unroll")                                                     \
      for (int _m = 0; _m < 4; ++_m) {                                      \
        _av[_m] = *(const bf16x8*)(&As[bufsel][aoff[_m] + coff[_kk]]);      \
        _bv[_m] = *(const bf16x8*)(&Bs[bufsel][boff[_m] + coff[_kk]]);      \
      }                                                                     \
      _Pragma("unroll")                                                     \
      for (int _m = 0; _m < 4; ++_m)                                        \
        _Pragma("unroll")                                                   \
        for (int _n = 0; _n < 4; ++_n)                                      \
          acc[_m][_n] = __builtin_amdgcn_mfma_f32_16x16x32_bf16(            \
              _av[_m], _bv[_n], acc[_m][_n], 0, 0, 0);                      \
    }                                                                       \
  } while (0)

  // prologue
  STAGE(0, 0);
  asm volatile("s_waitcnt vmcnt(0)" ::: "memory");
  __syncthreads();

  // 2-phase main loop: prefetch kt+1 into buf^1 while computing buf
  int cur = 0;
#pragma unroll 1
  for (int kt = 0; kt < (DDIM / 64) - 1; ++kt) {
    if (cur == 0) { STAGE(1, kt + 1); COMPUTE(0); }
    else          { STAGE(0, kt + 1); COMPUTE(1); }
    __syncthreads();   // vmcnt(0)+lgkmcnt(0)+barrier: next tile landed
    cur ^= 1;
  }
  if (cur == 0) COMPUTE(0); else COMPUTE(1);

#undef STAGE
#undef COMPUTE

  // ---------- epilogue ----------
  const int rbase = bi * 128 + wrow * 64;
  const int cbase = bj * 128 + wcol * 64;
  const float w = (bi == bj) ? 1.0f : 2.0f;

  float sqr[16], rnr[16];
  int   yr[16];
#pragma unroll
  for (int m = 0; m < 4; ++m)
#pragma unroll
    for (int v = 0; v < 4; ++v) {
      int gi = rbase + m * 16 + (lane >> 4) * 4 + v;
      sqr[m * 4 + v] = sq[gi];
      rnr[m * 4 + v] = rn[gi];
      yr[m * 4 + v]  = y[gi];
    }
  float sqc[4], rnc[4];
  int   yc[4];
#pragma unroll
  for (int n = 0; n < 4; ++n) {
    int gj = cbase + n * 16 + (lane & 15);
    sqc[n] = sq[gj];
    rnc[n] = rn[gj];
    yc[n]  = y[gj];
  }

  float lsum = 0.f;
#pragma unroll
  for (int m = 0; m < 4; ++m)
#pragma unroll
    for (int n = 0; n < 4; ++n)
#pragma unroll
      for (int v = 0; v < 4; ++v) {
        float g  = acc[m][n][v];
        float d2 = sqr[m * 4 + v] + sqc[n] - 2.0f * g;
        float dist = d2 > 0.f ? sqrtf(d2) : 0.f;
        float sim  = g * rnr[m * 4 + v] * rnc[n];
        float sgn  = (yr[m * 4 + v] == yc[n]) ? 1.0f : -1.0f;
        lsum += sgn * (dist - sim);
      }
  lsum *= w;

#pragma unroll
  for (int off = 32; off; off >>= 1) lsum += __shfl_down(lsum, off);
  __shared__ float wsum[4];
  if (lane == 0) wsum[wid] = lsum;
  __syncthreads();
  if (tid == 0) partials[blockIdx.x] = wsum[0] + wsum[1] + wsum[2] + wsum[3];
}

// ---------------- deterministic final reduce ----------------
extern "C" __global__ void __launch_bounds__(256) reduce_kernel(
    const float* __restrict__ partials, float* __restrict__ out) {
  float s = 0.f;
  for (int i = threadIdx.x; i < NBLK; i += 256) s += partials[i];
#pragma unroll
  for (int off = 32; off; off >>= 1) s += __shfl_down(s, off);
  __shared__ float ws[4];
  if ((threadIdx.x & 63) == 0) ws[threadIdx.x >> 6] = s;
  __syncthreads();
  if (threadIdx.x == 0) out[0] = ws[0] + ws[1] + ws[2] + ws[3];
}

extern "C" void kernel_launch(void* const* d_in, const int* in_sizes, int n_in,
                              void* d_out, int out_size, void* d_ws, size_t ws_size,
                              hipStream_t stream) {
  const float* F = (const float*)d_in[0];
  const int*   y = (const int*)d_in[1];
  float* out = (float*)d_out;

  ushort* Fb = (ushort*)d_ws;                                 // 8 MB bf16
  float*  sq = (float*)((char*)d_ws + (size_t)NROWS * DDIM * 2);
  float*  rn = sq + NROWS;
  float*  partials = rn + NROWS;

  prep_kernel<<<NROWS / 4, 256, 0, stream>>>(F, Fb, sq, rn);
  gram_kernel<<<NBLK, 256, 0, stream>>>(Fb, sq, rn, y, partials);
  reduce_kernel<<<1, 256, 0, stream>>>(partials, out);
}